// Round 12
// baseline (64.218 us; speedup 1.0000x reference)
//
#include <hip/hip_runtime.h>

#define MM    32768
#define OUTN  65536
#define NBC   64                  // output blocks of 1024 bins
#define NSTW  16                  // i0-steps (of 32 limbs) per workgroup
#define APL   1536                // revA bytes per digit plane (1504 live, pad)
#define BPL   608                 // B-phase bytes per (plane,phase) (543 live, pad)
#define BOFF  (3 * APL)           // 4608
#define ABSZ  (BOFF + 12 * BPL)   // 11904 bytes of A/B staging
#define TPB   256                 // 4 waves; each wave owns 4 of the 16 steps
#define NPASS 6                   // DIAGNOSTIC: step-loop repetitions (result identical)

typedef int i32x4  __attribute__((ext_vector_type(4)));
typedef int i32x16 __attribute__((ext_vector_type(16)));

// Per output block b (c0 = 1024b): i-sweep start (aligned) and 16-step units.
__host__ __device__ inline void blk_params(int b, int* Istart, int* units) {
    const int c0 = b << 10;
    int iLo = c0 - (MM - 1); if (iLo < 0) iLo = 0;
    int iHi = c0 + 1023;     if (iHi > MM - 1) iHi = MM - 1;
    const int Is = (iLo - 961) & ~31;
    const int Ie = (iHi + 31) & ~31;
    const int steps = ((Ie - Is) >> 5) + 1;
    *Istart = Is;
    *units  = (steps + NSTW - 1) / NSTW;
}

// A-read swizzle (verified R9/R10).
__device__ __forceinline__ int swzA(int a) {
    return a ^ ((a >> 2) & 0x30) ^ ((a >> 4) & 0x30);
}
__device__ __forceinline__ unsigned ldv(const int* __restrict__ p, int x) {
    return ((unsigned)x < (unsigned)MM) ? (unsigned)p[x] : 0u;
}
__device__ __forceinline__ unsigned pk4(unsigned b0, unsigned b1, unsigned b2, unsigned b3) {
    return b0 | (b1 << 8) | (b2 << 16) | (b3 << 24);
}
__device__ __forceinline__ i32x16 z16() {
    i32x16 v;
#pragma unroll
    for (int i = 0; i < 16; ++i) v[i] = 0;
    return v;
}

// DIAGNOSTIC build: the step loop runs NPASS times (each pass parks into
// red[] across a barrier -> kept live; later passes overwrite the same slots
// with identical values). Output is bit-identical to the single-pass kernel.
template <bool PARTIAL>
__global__ __launch_bounds__(TPB, 4) void conv_mfma(
    const int* __restrict__ A, const int* __restrict__ B,
    unsigned* __restrict__ part, unsigned* __restrict__ out)
{
    __shared__ __align__(16) char lds[ABSZ];      // A/B staging (disjoint)
    __shared__ __align__(16) unsigned red[4096];  // 4 waves x 1024 bins

    int id = (int)blockIdx.x, blk = 0, Istart = 0, un = 0;
#pragma unroll 1
    for (; blk < NBC; ++blk) {
        blk_params(blk, &Istart, &un);
        if (id < un) break;
        id -= un;
    }
    const int c0   = blk << 10;
    const int S0   = Istart + 512 * id;
    const int ATop = S0 + 1472;
    const int JB   = c0 - S0 - 480;
    const int l    = (int)threadIdx.x;

    // ---- Stage A (376 dwords x 3 planes) ----
#pragma unroll
    for (int it = 0; it < 2; ++it) {
        const int w = l + (it << 8);
        if (w < 376) {
            const int x0 = ATop - 4 * w;
            const unsigned v0 = ldv(A, x0),     v1 = ldv(A, x0 - 1);
            const unsigned v2 = ldv(A, x0 - 2), v3 = ldv(A, x0 - 3);
            const int wa = swzA(4 * w);
            *(unsigned*)&lds[0 * APL + wa] = pk4(v0 & 127, v1 & 127, v2 & 127, v3 & 127);
            *(unsigned*)&lds[1 * APL + wa] = pk4((v0 >> 7) & 127, (v1 >> 7) & 127,
                                                 (v2 >> 7) & 127, (v3 >> 7) & 127);
            *(unsigned*)&lds[2 * APL + wa] = pk4(v0 >> 14, v1 >> 14, v2 >> 14, v3 >> 14);
        }
    }

    // ---- Stage B (144 dwords x 3 planes x 4 byte-phases) ----
    if (l < 144) {
        const int j = JB + 4 * l;
        const unsigned u0 = ldv(B, j),     u1 = ldv(B, j + 1), u2 = ldv(B, j + 2);
        const unsigned u3 = ldv(B, j + 3), u4 = ldv(B, j + 4), u5 = ldv(B, j + 5);
        const unsigned u6 = ldv(B, j + 6);
        const int wb = BOFF + 4 * l;
#define BPLANE(q, D0, D1, D2, D3, D4, D5, D6)                                   \
        *(unsigned*)&lds[wb + ((q)*4 + 0) * BPL] = pk4(D0, D1, D2, D3);         \
        *(unsigned*)&lds[wb + ((q)*4 + 1) * BPL] = pk4(D1, D2, D3, D4);         \
        *(unsigned*)&lds[wb + ((q)*4 + 2) * BPL] = pk4(D2, D3, D4, D5);         \
        *(unsigned*)&lds[wb + ((q)*4 + 3) * BPL] = pk4(D3, D4, D5, D6);
        BPLANE(0, u0 & 127, u1 & 127, u2 & 127, u3 & 127, u4 & 127, u5 & 127, u6 & 127)
        BPLANE(1, (u0 >> 7) & 127, (u1 >> 7) & 127, (u2 >> 7) & 127,
                  (u3 >> 7) & 127, (u4 >> 7) & 127, (u5 >> 7) & 127, (u6 >> 7) & 127)
        BPLANE(2, u0 >> 14, u1 >> 14, u2 >> 14, u3 >> 14, u4 >> 14, u5 >> 14, u6 >> 14)
#undef BPLANE
    }
    __syncthreads();

    const int wv = l >> 6;
    const int ll = l & 63;
    const int n  = ll & 31, h = ll >> 5;
    const int aInv = 1472 + 16 * h - 32 * n;
    const int bInv = BOFF + (n & 3) * BPL + 4 * (120 + 4 * h + (n >> 2));

#pragma unroll 1
    for (int pass = 0; pass < NPASS; ++pass) {
        i32x16 acc0 = z16(), acc1 = z16(), acc2 = z16(), acc3 = z16(), acc4 = z16();

#pragma unroll
        for (int j = 0; j < 4; ++j) {
            const int s = wv + 4 * j;
            const int aa = swzA(aInv - 32 * s);
            const i32x4 a0 = *(const i32x4*)&lds[0 * APL + aa];
            const i32x4 a1 = *(const i32x4*)&lds[1 * APL + aa];
            const i32x4 a2 = *(const i32x4*)&lds[2 * APL + aa];
            const int bb = bInv - 32 * s;
            i32x4 b0, b1, b2;
#pragma unroll
            for (int q = 0; q < 4; ++q) {
                b0[q] = *(const int*)&lds[bb + 0 * 4 * BPL + 4 * q];
                b1[q] = *(const int*)&lds[bb + 1 * 4 * BPL + 4 * q];
                b2[q] = *(const int*)&lds[bb + 2 * 4 * BPL + 4 * q];
            }
            acc0 = __builtin_amdgcn_mfma_i32_32x32x32_i8(a0, b0, acc0, 0, 0, 0);
            acc1 = __builtin_amdgcn_mfma_i32_32x32x32_i8(a0, b1, acc1, 0, 0, 0);
            acc2 = __builtin_amdgcn_mfma_i32_32x32x32_i8(a0, b2, acc2, 0, 0, 0);
            acc3 = __builtin_amdgcn_mfma_i32_32x32x32_i8(a1, b2, acc3, 0, 0, 0);
            acc4 = __builtin_amdgcn_mfma_i32_32x32x32_i8(a2, b2, acc4, 0, 0, 0);
            acc1 = __builtin_amdgcn_mfma_i32_32x32x32_i8(a1, b0, acc1, 0, 0, 0);
            acc2 = __builtin_amdgcn_mfma_i32_32x32x32_i8(a1, b1, acc2, 0, 0, 0);
            acc3 = __builtin_amdgcn_mfma_i32_32x32x32_i8(a2, b1, acc3, 0, 0, 0);
            acc2 = __builtin_amdgcn_mfma_i32_32x32x32_i8(a2, b0, acc2, 0, 0, 0);
        }

#pragma unroll
        for (int r = 0; r < 16; ++r) {
            const unsigned v = (unsigned)acc0[r]
                             + ((unsigned)acc1[r] << 7)
                             + ((unsigned)acc2[r] << 14)
                             + ((unsigned)acc3[r] << 21)
                             + ((unsigned)acc4[r] << 28);
            const int idx = 32 * ((r & 3) + 8 * (r >> 2) + 4 * h) + n;
            red[(wv << 10) + idx] = v;
        }
        __syncthreads();
    }

    // Cross-wave sum: lane l owns bins 4l..4l+3.
    const uint4* rb = (const uint4*)red;
    uint4 t0 = rb[l], t1 = rb[256 + l], t2 = rb[512 + l], t3 = rb[768 + l];
    const uint4 tot = make_uint4(t0.x + t1.x + t2.x + t3.x,
                                 t0.y + t1.y + t2.y + t3.y,
                                 t0.z + t1.z + t2.z + t3.z,
                                 t0.w + t1.w + t2.w + t3.w);
    if (PARTIAL) {
        *(uint4*)&part[((size_t)blockIdx.x << 10) + 4 * l] = tot;
    } else {
        unsigned* o = out + c0 + 4 * l;
        atomicAdd(&o[0], tot.x); atomicAdd(&o[1], tot.y);
        atomicAdd(&o[2], tot.z); atomicAdd(&o[3], tot.w);
    }
}

// out[c] = sum over the owning block's unit slices (mod 2^32).
__global__ __launch_bounds__(256) void reduce_k(
    const unsigned* __restrict__ part, unsigned* __restrict__ out)
{
    const int c = (int)blockIdx.x * 256 + (int)threadIdx.x;
    const int blk = c >> 10;

    int base = 0, un = 0, Is = 0;
#pragma unroll 1
    for (int b = 0; b < NBC; ++b) {
        blk_params(b, &Is, &un);
        if (b == blk) break;
        base += un;
    }

    const unsigned* p = part + ((size_t)base << 10) + (c & 1023);
    unsigned s0 = 0, s1 = 0, s2 = 0, s3 = 0;
    int i = 0;
#pragma unroll 1
    for (; i + 4 <= un; i += 4) {
        s0 += p[(size_t)(i + 0) << 10]; s1 += p[(size_t)(i + 1) << 10];
        s2 += p[(size_t)(i + 2) << 10]; s3 += p[(size_t)(i + 3) << 10];
    }
    for (; i < un; ++i) s0 += p[(size_t)i << 10];
    out[c] = s0 + s1 + s2 + s3;
}

extern "C" void kernel_launch(void* const* d_in, const int* in_sizes, int n_in,
                              void* d_out, int out_size, void* d_ws, size_t ws_size,
                              hipStream_t stream)
{
    const int* A = (const int*)d_in[0];
    const int* B = (const int*)d_in[1];
    unsigned* out = (unsigned*)d_out;
    unsigned* ws = (unsigned*)d_ws;

    int NU = 0;
    for (int b = 0; b < NBC; ++b) {
        int Is, un;
        blk_params(b, &Is, &un);
        NU += un;
    }

    const size_t need = (size_t)NU * 1024 * sizeof(unsigned);
    if (ws_size >= need) {
        conv_mfma<true><<<NU, TPB, 0, stream>>>(A, B, ws, out);
        reduce_k<<<OUTN / 256, 256, 0, stream>>>(ws, out);
    } else {
        hipMemsetAsync(d_out, 0, (size_t)out_size * sizeof(int), stream);
        conv_mfma<false><<<NU, TPB, 0, stream>>>(A, B, nullptr, out);
    }
}

// Round 13
// 29.264 us; speedup vs baseline: 2.1944x; 2.1944x over previous
//
#include <hip/hip_runtime.h>

#define MM      32768
#define OUTN    65536
#define NBC     64                 // output blocks of 1024 bins
#define NSTW    16                 // i0-steps per workgroup
#define APL     1536               // revA bytes per digit plane in LDS
#define BPL     608                // B-phase bytes per (plane,phase) in LDS
#define BOFF    (3 * APL)          // 4608
#define ABSZ    (BOFF + 12 * BPL)  // 11904 bytes A/B staging
#define TPB     256
#define MAXU    66                 // max units per block (b=31/32)
#define AMAXTOP 34816              // global reversed-A origin (mult of 32)
#define GASZ    9216               // dwords per gRA plane
#define GBSZ    9216               // dwords per gB (q,r) plane
#define GBGUARD 512                // leading zero-guard dwords in gB
#define GA_OFS  0
#define GB_OFS  (3 * GASZ)         // 27648
#define PART_OFS (GB_OFS + 12 * GBSZ)  // 138240

typedef int i32x4  __attribute__((ext_vector_type(4)));
typedef int i32x16 __attribute__((ext_vector_type(16)));

__host__ __device__ inline void blk_params(int b, int* Istart, int* units) {
    const int c0 = b << 10;
    int iLo = c0 - (MM - 1); if (iLo < 0) iLo = 0;
    int iHi = c0 + 1023;     if (iHi > MM - 1) iHi = MM - 1;
    const int Is = (iLo - 961) & ~31;
    const int Ie = (iHi + 31) & ~31;
    const int steps = ((Ie - Is) >> 5) + 1;
    *Istart = Is;
    *units  = (steps + NSTW - 1) / NSTW;
}

__device__ __forceinline__ int swzA(int a) {
    return a ^ ((a >> 2) & 0x30) ^ ((a >> 4) & 0x30);
}
__device__ __forceinline__ unsigned ldv(const int* __restrict__ p, int x) {
    return ((unsigned)x < (unsigned)MM) ? (unsigned)p[x] : 0u;
}
__device__ __forceinline__ unsigned pk4(unsigned b0, unsigned b1, unsigned b2, unsigned b3) {
    return b0 | (b1 << 8) | (b2 << 16) | (b3 << 24);
}
__device__ __forceinline__ i32x16 z16() {
    i32x16 v;
#pragma unroll
    for (int i = 0; i < 16; ++i) v[i] = 0;
    return v;
}

// Build guard-padded digit planes (zeros outside [0,MM)):
//  gRA_p[x] = pk4(dp(A[T-4x]), dp(A[T-4x-1]), dp(A[T-4x-2]), dp(A[T-4x-3])), T=AMAXTOP
//  gB[q*4+r][w] = pk4(dq(B[4(w-G)+r+0..3])), G=GBGUARD
__global__ __launch_bounds__(TPB) void pack_kernel(
    const int* __restrict__ A, const int* __restrict__ B, unsigned* __restrict__ ws)
{
    const int idx = (int)blockIdx.x * TPB + (int)threadIdx.x;
    if (idx < GASZ) {
        const int x0 = AMAXTOP - 4 * idx;
        const unsigned v0 = ldv(A, x0),     v1 = ldv(A, x0 - 1);
        const unsigned v2 = ldv(A, x0 - 2), v3 = ldv(A, x0 - 3);
        ws[GA_OFS + 0 * GASZ + idx] = pk4(v0 & 127, v1 & 127, v2 & 127, v3 & 127);
        ws[GA_OFS + 1 * GASZ + idx] = pk4((v0 >> 7) & 127, (v1 >> 7) & 127,
                                          (v2 >> 7) & 127, (v3 >> 7) & 127);
        ws[GA_OFS + 2 * GASZ + idx] = pk4(v0 >> 14, v1 >> 14, v2 >> 14, v3 >> 14);
    } else if (idx < GASZ + 4 * GBSZ) {
        const int y = idx - GASZ;
        const int r = y / GBSZ, w0 = y - r * GBSZ;
        const int base = 4 * (w0 - GBGUARD) + r;
        const unsigned u0 = ldv(B, base),     u1 = ldv(B, base + 1);
        const unsigned u2 = ldv(B, base + 2), u3 = ldv(B, base + 3);
        ws[GB_OFS + (0 * 4 + r) * GBSZ + w0] = pk4(u0 & 127, u1 & 127, u2 & 127, u3 & 127);
        ws[GB_OFS + (1 * 4 + r) * GBSZ + w0] = pk4((u0 >> 7) & 127, (u1 >> 7) & 127,
                                                   (u2 >> 7) & 127, (u3 >> 7) & 127);
        ws[GB_OFS + (2 * 4 + r) * GBSZ + w0] = pk4(u0 >> 14, u1 >> 14, u2 >> 14, u3 >> 14);
    }
}

// One workgroup = one unit (blk = blockIdx.y, id = blockIdx.x); staging is a
// pure guard-safe dword copy from the pre-packed planes. Step loop, fragment
// maps and epilogue byte-identical to the R10 kernel (verified absmax 0).
template <bool PARTIAL>
__global__ __launch_bounds__(TPB, 4) void conv_mfma(
    const unsigned* __restrict__ gRA, const unsigned* __restrict__ gB,
    unsigned* __restrict__ part, unsigned* __restrict__ out)
{
    __shared__ __align__(16) char lds[ABSZ];
    __shared__ __align__(16) unsigned red[4096];

    const int blk = (int)blockIdx.y;
    const int id  = (int)blockIdx.x;
    int Istart, un;
    blk_params(blk, &Istart, &un);
    if (id >= un) return;

    const int c0   = blk << 10;
    const int S0   = Istart + 512 * id;
    const int ATop = S0 + 1472;
    const int JB   = c0 - S0 - 480;
    const int l    = (int)threadIdx.x;

    // ---- Stage A: straight copy of 376 dwords x 3 planes (swizzled dest) ----
    const int OFA = (AMAXTOP - ATop) >> 2;
#pragma unroll
    for (int it = 0; it < 2; ++it) {
        const int w = l + (it << 8);
        if (w < 376) {
            const int wa = swzA(4 * w);
            *(unsigned*)&lds[0 * APL + wa] = gRA[0 * GASZ + OFA + w];
            *(unsigned*)&lds[1 * APL + wa] = gRA[1 * GASZ + OFA + w];
            *(unsigned*)&lds[2 * APL + wa] = gRA[2 * GASZ + OFA + w];
        }
    }

    // ---- Stage B: straight copy of 144 dwords x 12 (q,r) planes ----
    const int OFB = GBGUARD + (JB >> 2);
    if (l < 144) {
#pragma unroll
        for (int qr = 0; qr < 12; ++qr) {
            *(unsigned*)&lds[BOFF + qr * BPL + 4 * l] = gB[qr * GBSZ + OFB + l];
        }
    }
    __syncthreads();

    const int wv = l >> 6;
    const int ll = l & 63;
    const int n  = ll & 31, h = ll >> 5;
    const int aInv = 1472 + 16 * h - 32 * n;
    const int bInv = BOFF + (n & 3) * BPL + 4 * (120 + 4 * h + (n >> 2));

    i32x16 acc0 = z16(), acc1 = z16(), acc2 = z16(), acc3 = z16(), acc4 = z16();

#pragma unroll
    for (int j = 0; j < 4; ++j) {
        const int s = wv + 4 * j;
        const int aa = swzA(aInv - 32 * s);
        const i32x4 a0 = *(const i32x4*)&lds[0 * APL + aa];
        const i32x4 a1 = *(const i32x4*)&lds[1 * APL + aa];
        const i32x4 a2 = *(const i32x4*)&lds[2 * APL + aa];
        const int bb = bInv - 32 * s;
        i32x4 b0, b1, b2;
#pragma unroll
        for (int q = 0; q < 4; ++q) {
            b0[q] = *(const int*)&lds[bb + 0 * 4 * BPL + 4 * q];
            b1[q] = *(const int*)&lds[bb + 1 * 4 * BPL + 4 * q];
            b2[q] = *(const int*)&lds[bb + 2 * 4 * BPL + 4 * q];
        }
        acc0 = __builtin_amdgcn_mfma_i32_32x32x32_i8(a0, b0, acc0, 0, 0, 0);
        acc1 = __builtin_amdgcn_mfma_i32_32x32x32_i8(a0, b1, acc1, 0, 0, 0);
        acc2 = __builtin_amdgcn_mfma_i32_32x32x32_i8(a0, b2, acc2, 0, 0, 0);
        acc3 = __builtin_amdgcn_mfma_i32_32x32x32_i8(a1, b2, acc3, 0, 0, 0);
        acc4 = __builtin_amdgcn_mfma_i32_32x32x32_i8(a2, b2, acc4, 0, 0, 0);
        acc1 = __builtin_amdgcn_mfma_i32_32x32x32_i8(a1, b0, acc1, 0, 0, 0);
        acc2 = __builtin_amdgcn_mfma_i32_32x32x32_i8(a1, b1, acc2, 0, 0, 0);
        acc3 = __builtin_amdgcn_mfma_i32_32x32x32_i8(a2, b1, acc3, 0, 0, 0);
        acc2 = __builtin_amdgcn_mfma_i32_32x32x32_i8(a2, b0, acc2, 0, 0, 0);
    }

    __syncthreads();
#pragma unroll
    for (int r = 0; r < 16; ++r) {
        const unsigned v = (unsigned)acc0[r]
                         + ((unsigned)acc1[r] << 7)
                         + ((unsigned)acc2[r] << 14)
                         + ((unsigned)acc3[r] << 21)
                         + ((unsigned)acc4[r] << 28);
        const int idx = 32 * ((r & 3) + 8 * (r >> 2) + 4 * h) + n;
        red[(wv << 10) + idx] = v;
    }
    __syncthreads();

    const uint4* rb = (const uint4*)red;
    uint4 t0 = rb[l], t1 = rb[256 + l], t2 = rb[512 + l], t3 = rb[768 + l];
    const uint4 tot = make_uint4(t0.x + t1.x + t2.x + t3.x,
                                 t0.y + t1.y + t2.y + t3.y,
                                 t0.z + t1.z + t2.z + t3.z,
                                 t0.w + t1.w + t2.w + t3.w);
    if (PARTIAL) {
        *(uint4*)&part[(((size_t)blk * MAXU + id) << 10) + 4 * l] = tot;
    } else {
        unsigned* o = out + c0 + 4 * l;
        atomicAdd(&o[0], tot.x); atomicAdd(&o[1], tot.y);
        atomicAdd(&o[2], tot.z); atomicAdd(&o[3], tot.w);
    }
}

// out[c] = sum over the owning block's valid unit slices (mod 2^32).
__global__ __launch_bounds__(TPB) void reduce_k(
    const unsigned* __restrict__ part, unsigned* __restrict__ out)
{
    const int c = (int)blockIdx.x * TPB + (int)threadIdx.x;
    const int blk = c >> 10;
    int Is, un;
    blk_params(blk, &Is, &un);

    const unsigned* p = part + (((size_t)blk * MAXU) << 10) + (c & 1023);
    unsigned s0 = 0, s1 = 0, s2 = 0, s3 = 0;
    int i = 0;
#pragma unroll 1
    for (; i + 4 <= un; i += 4) {
        s0 += p[(size_t)(i + 0) << 10]; s1 += p[(size_t)(i + 1) << 10];
        s2 += p[(size_t)(i + 2) << 10]; s3 += p[(size_t)(i + 3) << 10];
    }
    for (; i < un; ++i) s0 += p[(size_t)i << 10];
    out[c] = s0 + s1 + s2 + s3;
}

// Fallback (ws too small): R10-style self-contained kernel, atomic output.
__global__ __launch_bounds__(TPB, 4) void conv_fb(
    const int* __restrict__ A, const int* __restrict__ B, unsigned* __restrict__ out)
{
    __shared__ __align__(16) char lds[ABSZ];
    __shared__ __align__(16) unsigned red[4096];

    int id = (int)blockIdx.x, blk = 0, Istart = 0, un = 0;
#pragma unroll 1
    for (; blk < NBC; ++blk) {
        blk_params(blk, &Istart, &un);
        if (id < un) break;
        id -= un;
    }
    const int c0 = blk << 10, S0 = Istart + 512 * id;
    const int ATop = S0 + 1472, JB = c0 - S0 - 480;
    const int l = (int)threadIdx.x;

#pragma unroll
    for (int it = 0; it < 2; ++it) {
        const int w = l + (it << 8);
        if (w < 376) {
            const int x0 = ATop - 4 * w;
            const unsigned v0 = ldv(A, x0), v1 = ldv(A, x0 - 1);
            const unsigned v2 = ldv(A, x0 - 2), v3 = ldv(A, x0 - 3);
            const int wa = swzA(4 * w);
            *(unsigned*)&lds[0 * APL + wa] = pk4(v0 & 127, v1 & 127, v2 & 127, v3 & 127);
            *(unsigned*)&lds[1 * APL + wa] = pk4((v0 >> 7) & 127, (v1 >> 7) & 127,
                                                 (v2 >> 7) & 127, (v3 >> 7) & 127);
            *(unsigned*)&lds[2 * APL + wa] = pk4(v0 >> 14, v1 >> 14, v2 >> 14, v3 >> 14);
        }
    }
    if (l < 144) {
        const int j = JB + 4 * l;
        const unsigned u0 = ldv(B, j), u1 = ldv(B, j + 1), u2 = ldv(B, j + 2);
        const unsigned u3 = ldv(B, j + 3), u4 = ldv(B, j + 4), u5 = ldv(B, j + 5);
        const unsigned u6 = ldv(B, j + 6);
        const int wb = BOFF + 4 * l;
#define BPLANE(q, D0, D1, D2, D3, D4, D5, D6)                                   \
        *(unsigned*)&lds[wb + ((q)*4 + 0) * BPL] = pk4(D0, D1, D2, D3);         \
        *(unsigned*)&lds[wb + ((q)*4 + 1) * BPL] = pk4(D1, D2, D3, D4);         \
        *(unsigned*)&lds[wb + ((q)*4 + 2) * BPL] = pk4(D2, D3, D4, D5);         \
        *(unsigned*)&lds[wb + ((q)*4 + 3) * BPL] = pk4(D3, D4, D5, D6);
        BPLANE(0, u0 & 127, u1 & 127, u2 & 127, u3 & 127, u4 & 127, u5 & 127, u6 & 127)
        BPLANE(1, (u0 >> 7) & 127, (u1 >> 7) & 127, (u2 >> 7) & 127,
                  (u3 >> 7) & 127, (u4 >> 7) & 127, (u5 >> 7) & 127, (u6 >> 7) & 127)
        BPLANE(2, u0 >> 14, u1 >> 14, u2 >> 14, u3 >> 14, u4 >> 14, u5 >> 14, u6 >> 14)
#undef BPLANE
    }
    __syncthreads();

    const int wv = l >> 6, ll = l & 63, n = ll & 31, h = ll >> 5;
    const int aInv = 1472 + 16 * h - 32 * n;
    const int bInv = BOFF + (n & 3) * BPL + 4 * (120 + 4 * h + (n >> 2));
    i32x16 acc0 = z16(), acc1 = z16(), acc2 = z16(), acc3 = z16(), acc4 = z16();
#pragma unroll
    for (int j = 0; j < 4; ++j) {
        const int s = wv + 4 * j;
        const int aa = swzA(aInv - 32 * s);
        const i32x4 a0 = *(const i32x4*)&lds[0 * APL + aa];
        const i32x4 a1 = *(const i32x4*)&lds[1 * APL + aa];
        const i32x4 a2 = *(const i32x4*)&lds[2 * APL + aa];
        const int bb = bInv - 32 * s;
        i32x4 b0, b1, b2;
#pragma unroll
        for (int q = 0; q < 4; ++q) {
            b0[q] = *(const int*)&lds[bb + 0 * 4 * BPL + 4 * q];
            b1[q] = *(const int*)&lds[bb + 1 * 4 * BPL + 4 * q];
            b2[q] = *(const int*)&lds[bb + 2 * 4 * BPL + 4 * q];
        }
        acc0 = __builtin_amdgcn_mfma_i32_32x32x32_i8(a0, b0, acc0, 0, 0, 0);
        acc1 = __builtin_amdgcn_mfma_i32_32x32x32_i8(a0, b1, acc1, 0, 0, 0);
        acc2 = __builtin_amdgcn_mfma_i32_32x32x32_i8(a0, b2, acc2, 0, 0, 0);
        acc3 = __builtin_amdgcn_mfma_i32_32x32x32_i8(a1, b2, acc3, 0, 0, 0);
        acc4 = __builtin_amdgcn_mfma_i32_32x32x32_i8(a2, b2, acc4, 0, 0, 0);
        acc1 = __builtin_amdgcn_mfma_i32_32x32x32_i8(a1, b0, acc1, 0, 0, 0);
        acc2 = __builtin_amdgcn_mfma_i32_32x32x32_i8(a1, b1, acc2, 0, 0, 0);
        acc3 = __builtin_amdgcn_mfma_i32_32x32x32_i8(a2, b1, acc3, 0, 0, 0);
        acc2 = __builtin_amdgcn_mfma_i32_32x32x32_i8(a2, b0, acc2, 0, 0, 0);
    }
    __syncthreads();
#pragma unroll
    for (int r = 0; r < 16; ++r) {
        const unsigned v = (unsigned)acc0[r] + ((unsigned)acc1[r] << 7)
                         + ((unsigned)acc2[r] << 14) + ((unsigned)acc3[r] << 21)
                         + ((unsigned)acc4[r] << 28);
        red[(wv << 10) + 32 * ((r & 3) + 8 * (r >> 2) + 4 * h) + n] = v;
    }
    __syncthreads();
    const uint4* rb = (const uint4*)red;
    uint4 t0 = rb[l], t1 = rb[256 + l], t2 = rb[512 + l], t3 = rb[768 + l];
    unsigned* o = out + c0 + 4 * l;
    atomicAdd(&o[0], t0.x + t1.x + t2.x + t3.x);
    atomicAdd(&o[1], t0.y + t1.y + t2.y + t3.y);
    atomicAdd(&o[2], t0.z + t1.z + t2.z + t3.z);
    atomicAdd(&o[3], t0.w + t1.w + t2.w + t3.w);
}

extern "C" void kernel_launch(void* const* d_in, const int* in_sizes, int n_in,
                              void* d_out, int out_size, void* d_ws, size_t ws_size,
                              hipStream_t stream)
{
    const int* A = (const int*)d_in[0];
    const int* B = (const int*)d_in[1];
    unsigned* out = (unsigned*)d_out;
    unsigned* ws = (unsigned*)d_ws;

    const size_t need = ((size_t)PART_OFS + (size_t)NBC * MAXU * 1024) * 4;  // ~17.9 MB
    if (ws_size >= need) {
        const int packN = GASZ + 4 * GBSZ;                    // 46080 threads
        pack_kernel<<<(packN + TPB - 1) / TPB, TPB, 0, stream>>>(A, B, ws);
        dim3 grid(MAXU, NBC);
        conv_mfma<true><<<grid, TPB, 0, stream>>>(ws + GA_OFS, ws + GB_OFS,
                                                  ws + PART_OFS, out);
        reduce_k<<<OUTN / TPB, TPB, 0, stream>>>(ws + PART_OFS, out);
    } else {
        hipMemsetAsync(d_out, 0, (size_t)out_size * sizeof(int), stream);
        int NU = 0;
        for (int b = 0; b < NBC; ++b) { int Is, un; blk_params(b, &Is, &un); NU += un; }
        conv_fb<<<NU, TPB, 0, stream>>>(A, B, out);
    }
}